// Round 4
// baseline (255.735 us; speedup 1.0000x reference)
//
#include <hip/hip_runtime.h>
#include <math.h>

#define LEVELS 16
#define FEAT 2

// Ns[l] = python round(16 * 1.5^l)  (banker's rounding; exact in fp32)
__constant__ float c_Ns[LEVELS] = {
    16.f, 24.f, 36.f, 54.f, 81.f, 122.f, 182.f, 273.f,
    410.f, 615.f, 923.f, 1384.f, 2076.f, 3114.f, 4671.f, 7006.f
};

#define P1 2654435761u
#define P2 805459861u

// POW2_TABLE: table size is power of two -> mask instead of %
// POW2_W    : row width is power of two -> shift/mask instead of div
template <bool POW2_TABLE, bool POW2_W>
__global__ __launch_bounds__(256) void hashenc_kernel(
    const float* __restrict__ x0,
    const float* __restrict__ y0,
    const float2* __restrict__ tables,
    const unsigned int* __restrict__ seeds,
    const int* __restrict__ tile_ptr,
    float* __restrict__ out,
    int N,              // H*W
    int W,              // row width
    int wshift,         // log2(W) when POW2_W
    unsigned int tsize, // table size (elements)
    unsigned int tmask) // tsize-1 when POW2_TABLE
{
    const int pix = blockIdx.x * blockDim.x + threadIdx.x;
    if (pix >= N) return;
    const int b = blockIdx.y;

    int i, j;
    if (POW2_W) {
        i = pix >> wshift;
        j = pix & (W - 1);
    } else {
        i = pix / W;
        j = pix - i * W;
    }

    // Reference computes scales = Ns / float(tile) in f32. When tile is a
    // power of two, mul-by-reciprocal is bit-exact (rcp of pow2 exact).
    // Otherwise fall back to true f32 division — a 1-ULP scale difference
    // can flip floorf at a cell boundary and change the hash entirely.
    const int tile = *tile_ptr;          // uniform scalar load
    const float tilef = (float)tile;
    float sc[LEVELS];
    if ((tile & (tile - 1)) == 0) {
        const float inv_tile = 1.0f / tilef;
#pragma unroll
        for (int l = 0; l < LEVELS; ++l) sc[l] = c_Ns[l] * inv_tile;
    } else {
#pragma unroll
        for (int l = 0; l < LEVELS; ++l) sc[l] = c_Ns[l] / tilef;
    }

    const float px = (float)j + x0[b];
    const float py = (float)i + y0[b];

    // out[b][l*2+f][pix], channel stride N
    float* outb = out + (size_t)b * (size_t)(LEVELS * FEAT) * (size_t)N + pix;

#pragma unroll
    for (int l = 0; l < LEVELS; ++l) {
        const float s = sc[l];
        const float xs = px * s;
        const float ys = py * s;
        const float fx0 = floorf(xs);
        const float fy0 = floorf(ys);
        const float fx = xs - fx0;
        const float fy = ys - fy0;
        const unsigned int ux = (unsigned int)(int)fx0;   // coords >= 0 always
        const unsigned int uy = (unsigned int)(int)fy0;

        const unsigned int sd = seeds[l];
        const unsigned int ax0 = ux * P1;
        const unsigned int ax1 = ax0 + P1;                // (ux+1)*P1 mod 2^32
        const unsigned int ay0 = (uy * P2) ^ sd;
        const unsigned int ay1 = (uy * P2 + P2) ^ sd;

        unsigned int i00, i10, i01, i11;
        if (POW2_TABLE) {
            i00 = (ax0 ^ ay0) & tmask;
            i10 = (ax1 ^ ay0) & tmask;
            i01 = (ax0 ^ ay1) & tmask;
            i11 = (ax1 ^ ay1) & tmask;
        } else {
            i00 = (ax0 ^ ay0) % tsize;
            i10 = (ax1 ^ ay0) % tsize;
            i01 = (ax0 ^ ay1) % tsize;
            i11 = (ax1 ^ ay1) % tsize;
        }

        const float2 f00 = tables[i00];
        const float2 f10 = tables[i10];
        const float2 f01 = tables[i01];
        const float2 f11 = tables[i11];

        const float omx = 1.0f - fx;
        const float omy = 1.0f - fy;
        const float w00 = omx * omy;
        const float w10 = fx * omy;
        const float w01 = omx * fy;
        const float w11 = fx * fy;

        const float e0 = w00 * f00.x + w10 * f10.x + w01 * f01.x + w11 * f11.x;
        const float e1 = w00 * f00.y + w10 * f10.y + w01 * f01.y + w11 * f11.y;

        // Non-temporal: don't let 128 MiB of streaming stores evict the
        // 4 MiB table from per-XCD L2 (table == entire L2 capacity).
        __builtin_nontemporal_store(e0, outb + (size_t)(2 * l) * (size_t)N);
        __builtin_nontemporal_store(e1, outb + (size_t)(2 * l + 1) * (size_t)N);
    }
}

extern "C" void kernel_launch(void* const* d_in, const int* in_sizes, int n_in,
                              void* d_out, int out_size, void* d_ws, size_t ws_size,
                              hipStream_t stream) {
    const float* x0 = (const float*)d_in[0];
    const float* y0 = (const float*)d_in[1];
    const float2* tables = (const float2*)d_in[2];
    const unsigned int* seeds = (const unsigned int*)d_in[3];
    // d_in[4] = memorized_crop_size (device scalar; geometry derived from out_size)
    const int* tile_ptr = (const int*)d_in[5];

    const int Bn = in_sizes[0];
    const unsigned int tsize = (unsigned int)(in_sizes[2] / FEAT);
    const int N = out_size / (Bn * LEVELS * FEAT);       // H*W
    const int W = (int)(sqrt((double)N) + 0.5);          // H == W in reference
    int wshift = 0;
    while ((1 << wshift) < W) ++wshift;

    float* out = (float*)d_out;

    dim3 grid((N + 255) / 256, Bn);
    dim3 block(256);

    const bool pow2_table = (tsize & (tsize - 1)) == 0;
    const bool pow2_w = (W & (W - 1)) == 0;

    if (pow2_table && pow2_w) {
        hashenc_kernel<true, true><<<grid, block, 0, stream>>>(
            x0, y0, tables, seeds, tile_ptr, out, N, W, wshift, tsize, tsize - 1u);
    } else if (pow2_table) {
        hashenc_kernel<true, false><<<grid, block, 0, stream>>>(
            x0, y0, tables, seeds, tile_ptr, out, N, W, wshift, tsize, tsize - 1u);
    } else if (pow2_w) {
        hashenc_kernel<false, true><<<grid, block, 0, stream>>>(
            x0, y0, tables, seeds, tile_ptr, out, N, W, wshift, tsize, 0u);
    } else {
        hashenc_kernel<false, false><<<grid, block, 0, stream>>>(
            x0, y0, tables, seeds, tile_ptr, out, N, W, wshift, tsize, 0u);
    }
}